// Round 1
// 473.596 us; speedup vs baseline: 1.0356x; 1.0356x over previous
//
#include <hip/hip_runtime.h>
#include <stdint.h>

typedef _Float16 f16_t;
typedef _Float16 f16x4 __attribute__((ext_vector_type(4)));
typedef _Float16 f16x8 __attribute__((ext_vector_type(8)));
typedef float f32x4 __attribute__((ext_vector_type(4)));

// ---------------------------------------------------------------------------
// async global->LDS, 16B per lane. LDS dest is wave-uniform base + lane*16.
// ---------------------------------------------------------------------------
__device__ __forceinline__ void async16(const void* g, void* lds) {
    typedef __attribute__((address_space(3))) void lds_void;
    typedef __attribute__((address_space(1))) void glb_void;
    lds_void* l = (lds_void*)(unsigned int)(unsigned long long)lds;
    glb_void* gp = (glb_void*)(unsigned long long)g;
    __builtin_amdgcn_global_load_lds(gp, l, 16, 0, 0);
}

// ---------------------------------------------------------------------------
// Fused: 3x weight fp32->fp16 + zero-init of the fp32 attn accumulator
// (needed because the split-K attn GEMM accumulates with atomicAdd).
// ---------------------------------------------------------------------------
__global__ void cvt3_zero(const float* __restrict__ a, f16_t* __restrict__ oa, int na,
                          const float* __restrict__ b, f16_t* __restrict__ ob, int nb,
                          const float* __restrict__ c, f16_t* __restrict__ oc, int nc,
                          float4* __restrict__ z, int nz4) {
    int i = blockIdx.x * 256 + threadIdx.x;
    if (i < na) oa[i] = (f16_t)a[i];
    if (i < nb) ob[i] = (f16_t)b[i];
    if (i < nc) oc[i] = (f16_t)c[i];
    if (i < nz4) { float4 zz; zz.x = 0.f; zz.y = 0.f; zz.z = 0.f; zz.w = 0.f; z[i] = zz; }
}

// ---------------------------------------------------------------------------
// Transpose + convert to fp16.  in: [R][S] per batch  ->  out: [S][R]
// 32x32 tiles via padded LDS, 256 threads. (Only needed for the fp32 inputs.)
// ---------------------------------------------------------------------------
template <typename TIN>
__global__ void transpose_cvt(const TIN* __restrict__ in, f16_t* __restrict__ out,
                              int R, int S, long long inStride, long long outStride) {
    __shared__ float tile[32][33];
    const int b = blockIdx.z;
    const TIN* ip = in + (long long)b * inStride;
    f16_t* op = out + (long long)b * outStride;
    const int s0 = blockIdx.x * 32;
    const int r0 = blockIdx.y * 32;
    const int t = threadIdx.x;
    const int lr = t >> 3;
    const int lc = (t & 7) * 4;

    const TIN* src = ip + (long long)(r0 + lr) * S + s0 + lc;
    float v0, v1, v2, v3;
    if (sizeof(TIN) == 4) {
        float4 v = *(const float4*)src;
        v0 = v.x; v1 = v.y; v2 = v.z; v3 = v.w;
    } else {
        f16x4 v = *(const f16x4*)src;
        v0 = (float)v[0]; v1 = (float)v[1]; v2 = (float)v[2]; v3 = (float)v[3];
    }
    tile[lr][lc + 0] = v0;
    tile[lr][lc + 1] = v1;
    tile[lr][lc + 2] = v2;
    tile[lr][lc + 3] = v3;
    __syncthreads();

    const int sr = t >> 3;
    const int rc = (t & 7) * 4;
    f16x4 o;
    o[0] = (f16_t)tile[rc + 0][sr];
    o[1] = (f16_t)tile[rc + 1][sr];
    o[2] = (f16_t)tile[rc + 2][sr];
    o[3] = (f16_t)tile[rc + 3][sr];
    *(f16x4*)(op + (long long)(s0 + sr) * R + r0 + rc) = o;
}

// ---------------------------------------------------------------------------
// bt-GEMM:  C[m,n] = sum_k A[m,k] * Bt[n,k]     (both K-contiguous, fp16)
// BK=32, 16x16x32 f16 MFMA, 256 threads = 4 waves (WM x WN), TM x TN tiles/wave.
// MODE 0: f16 C.
// MODE 1: fp32 C.
// MODE 2: f16  gamma*acc + resid.
// MODE 3: f16 C  +  f16 C^T dual-write (LDS-staged transpose, coalesced).
// MODE 5: fp32 atomicAdd (split-K partial sums), KSPLIT slices over blockIdx.z.
// ---------------------------------------------------------------------------
template <int BM, int BN, int TM, int TN, int WM, int WN, int MODE, int KSPLIT>
__global__ __launch_bounds__(256, 2)
void gemm_bt(const f16_t* __restrict__ A, const f16_t* __restrict__ B,
             void* __restrict__ C, const f16_t* __restrict__ resid,
             const float* __restrict__ gamma, f16_t* __restrict__ Ct,
             int M, int N, int K,
             long long strideA, long long strideB, long long strideC,
             long long strideCt) {
    constexpr int BK = 32;
    __shared__ __align__(16) f16_t As[BM * BK];
    __shared__ __align__(16) f16_t Bs[BN * BK];
    // transpose staging tile for MODE 3: [BN][BM+8] (row stride 272B: 16B-aligned,
    // bank-stride 68 dwords == 4 mod 32 -> ~2-way on b64/b128 ops, free)
    __shared__ __align__(16) f16_t Lt[(MODE == 3) ? BN * (BM + 8) : 1];

    const int tid = threadIdx.x;
    const int wave = tid >> 6;
    const int lane = tid & 63;
    const int wm = wave / WN;
    const int wn = wave % WN;
    const int l16 = lane & 15;
    const int l4 = lane >> 4;

    const long long zb = (KSPLIT == 1) ? blockIdx.z : (blockIdx.z / KSPLIT);
    const int ks = (KSPLIT == 1) ? 0 : (blockIdx.z % KSPLIT);
    const int Ksl = K / KSPLIT;
    const f16_t* Ab = A + zb * strideA + (long long)blockIdx.y * BM * K;
    const f16_t* Bb = B + zb * strideB + (long long)blockIdx.x * BN * K;

    f32x4 zero = {0.f, 0.f, 0.f, 0.f};
    f32x4 acc[TM][TN];
#pragma unroll
    for (int i = 0; i < TM; ++i)
#pragma unroll
        for (int j = 0; j < TN; ++j) acc[i][j] = zero;

    const int kBeg = ks * Ksl;
    for (int k0 = kBeg; k0 < kBeg + Ksl; k0 += BK) {
        // stage A tile: BM rows x 64B, 16B segs, seg id follows lane order
#pragma unroll
        for (int r = 0; r < (BM * 4) / 256; ++r) {
            int seg = r * 256 + tid;
            const f16_t* g = Ab + (long long)(seg >> 2) * K + k0 + (seg & 3) * 8;
            async16(g, &As[(r * 256 + wave * 64) * 8]);
        }
#pragma unroll
        for (int r = 0; r < (BN * 4) / 256; ++r) {
            int seg = r * 256 + tid;
            const f16_t* g = Bb + (long long)(seg >> 2) * K + k0 + (seg & 3) * 8;
            async16(g, &Bs[(r * 256 + wave * 64) * 8]);
        }
        __syncthreads();

        f16x8 af[TM], bfr[TN];
#pragma unroll
        for (int i = 0; i < TM; ++i)
            af[i] = *(const f16x8*)&As[((wm * TM + i) * 16 + l16) * BK + l4 * 8];
#pragma unroll
        for (int j = 0; j < TN; ++j)
            bfr[j] = *(const f16x8*)&Bs[((wn * TN + j) * 16 + l16) * BK + l4 * 8];
#pragma unroll
        for (int i = 0; i < TM; ++i)
#pragma unroll
            for (int j = 0; j < TN; ++j)
                acc[i][j] = __builtin_amdgcn_mfma_f32_16x16x32_f16(af[i], bfr[j], acc[i][j], 0, 0, 0);
        __syncthreads();
    }

    // epilogue: C/D layout col = lane&15, row = (lane>>4)*4 + reg
    const int row0 = blockIdx.y * BM + wm * TM * 16;
    const int col0 = blockIdx.x * BN + wn * TN * 16;
    float g = (MODE == 2) ? gamma[0] : 0.f;
#pragma unroll
    for (int i = 0; i < TM; ++i) {
#pragma unroll
        for (int j = 0; j < TN; ++j) {
            f16x4 tq;
#pragma unroll
            for (int r = 0; r < 4; ++r) {
                int row = row0 + i * 16 + l4 * 4 + r;
                int col = col0 + j * 16 + l16;
                long long idx = zb * strideC + (long long)row * N + col;
                float v = acc[i][j][r];
                if (MODE == 0) {
                    ((f16_t*)C)[idx] = (f16_t)v;
                } else if (MODE == 1) {
                    ((float*)C)[idx] = v;
                } else if (MODE == 2) {
                    float im = (float)resid[idx];
                    ((f16_t*)C)[idx] = (f16_t)(g * v + im);
                } else if (MODE == 3) {
                    ((f16_t*)C)[idx] = (f16_t)v;
                    tq[r] = (f16_t)v;
                } else if (MODE == 5) {
                    atomicAdd(&((float*)C)[idx], v);
                }
            }
            if (MODE == 3) {
                // local (row, col) within the block tile; rows r=0..3 are
                // contiguous in the transposed layout -> one 8B ds_write
                int rl = wm * (TM * 16) + i * 16 + l4 * 4;
                int cl = wn * (TN * 16) + j * 16 + l16;
                *(f16x4*)&Lt[cl * (BM + 8) + rl] = tq;
            }
        }
    }

    if (MODE == 3) {
        __syncthreads();
        const int bx0 = blockIdx.x * BN;
        const int by0 = blockIdx.y * BM;
        const long long cb = zb * strideCt;
#pragma unroll
        for (int it = 0; it < (BM * BN) / 2048; ++it) {
            int nl = it * 16 + (tid >> 4);
            int c8 = (tid & 15) * 8;
            f16x8 v = *(const f16x8*)&Lt[nl * (BM + 8) + c8];
            *(f16x8*)&Ct[cb + (long long)(bx0 + nl) * M + by0 + c8] = v;
        }
    }
}

// ---------------------------------------------------------------------------
// softmax over rows of 256 fp32 -> fp16.  One wave per row, 4 rows per block.
// ---------------------------------------------------------------------------
__global__ void softmax256(const float* __restrict__ attn, f16_t* __restrict__ out) {
    const int row = blockIdx.x * 4 + (threadIdx.x >> 6);
    const int lane = threadIdx.x & 63;
    const float4 v = *(const float4*)(attn + (long long)row * 256 + lane * 4);
    float m = fmaxf(fmaxf(v.x, v.y), fmaxf(v.z, v.w));
#pragma unroll
    for (int off = 32; off > 0; off >>= 1) m = fmaxf(m, __shfl_xor(m, off, 64));
    float e0 = __expf(v.x - m), e1 = __expf(v.y - m);
    float e2 = __expf(v.z - m), e3 = __expf(v.w - m);
    float s = e0 + e1 + e2 + e3;
#pragma unroll
    for (int off = 32; off > 0; off >>= 1) s += __shfl_xor(s, off, 64);
    const float inv = 1.0f / s;
    f16x4 o;
    o[0] = (f16_t)(e0 * inv);
    o[1] = (f16_t)(e1 * inv);
    o[2] = (f16_t)(e2 * inv);
    o[3] = (f16_t)(e3 * inv);
    *(f16x4*)(out + (long long)row * 256 + lane * 4) = o;
}

// ---------------------------------------------------------------------------
// Orchestration
//
// Dataflow (T = transposed layout, produced by GEMM epilogues, not kernels):
//   img  [C,N] + imgT [N,C]  <- G1 (dual-write)
//   kvT  [N,C] + kv   [C,N]  <- G2 (A=x2t: native output IS kvT; kv is dual)
//   attn [C,C] fp32          <- G3 split-K=4, atomicAdd (pre-zeroed)
//   attns[C,C] f16           <- softmax
//   yT   [N,C]               <- G4 = gamma*(kvT x attns^T) + imgT  (native, no y!)
//   out  [OC,N] fp32         <- G5 = w_out x yT^T
// ---------------------------------------------------------------------------
extern "C" void kernel_launch(void* const* d_in, const int* in_sizes, int n_in,
                              void* d_out, int out_size, void* d_ws, size_t ws_size,
                              hipStream_t stream) {
    (void)in_sizes; (void)n_in; (void)out_size; (void)ws_size;

    const float* x1 = (const float*)d_in[0];     // [16,512,64,64]
    const float* x2 = (const float*)d_in[1];     // [16,320,64,64]
    const float* w_img = (const float*)d_in[2];  // [256,512]
    const float* w_txt = (const float*)d_in[3];  // [256,320]
    const float* w_out = (const float*)d_in[4];  // [512,256]
    const float* gamma = (const float*)d_in[5];  // [1]

    constexpr int B = 16, C1 = 512, C2 = 320, C = 256, N = 4096, OC = 512;
    constexpr long long NC = (long long)N * C;       // 1048576
    constexpr long long CC = (long long)C * C;       // 65536

    // ws layout (bytes): peak 101,351,424 (~96.7 MiB)
    char* ws = (char*)d_ws;
    f16_t* wib  = (f16_t*)(ws + 0);          // 256*512*2    = 262144
    f16_t* wtb  = (f16_t*)(ws + 262144);     // 256*320*2    = 163840
    f16_t* wob  = (f16_t*)(ws + 425984);     // 512*256*2    = 262144
    f16_t* img  = (f16_t*)(ws + 688128);     // 16*NC*2      = 33554432
    f16_t* imgT = (f16_t*)(ws + 34242560);   // 33554432
    f16_t* kvT  = (f16_t*)(ws + 67796992);   // 33554432 -> ends 101351424
    f16_t* yT   = img;                       // reuse: img dead after G3

    // d_out used as scratch; final G5 overwrites all of it
    char* oc = (char*)d_out;
    f16_t* x1t   = (f16_t*)(oc);              // [0, 67108864)
    f16_t* x2t   = (f16_t*)(oc + 67108864);   // [.., 109051904)
    f16_t* kv    = (f16_t*)(oc);              // [0, 33554432)   after x1t dead (G1)
    float* attn  = (float*)(oc + 109051904);  // 4194304
    f16_t* attns = (f16_t*)(oc + 113246208);  // 2097152 -> ends 115343360

    // 1. weights -> f16, attn accumulator -> 0  (single launch)
    cvt3_zero<<<1024, 256, 0, stream>>>(w_img, wib, C * C1,
                                        w_txt, wtb, C * C2,
                                        w_out, wob, OC * C,
                                        (float4*)attn, (int)(B * CC / 4));

    // 2. x1 [C1,N] -> x1t [N,C1] f16 ; x2 -> x2t [N,C2]
    transpose_cvt<float><<<dim3(N / 32, C1 / 32, B), 256, 0, stream>>>(
        x1, x1t, C1, N, (long long)C1 * N, (long long)N * C1);
    transpose_cvt<float><<<dim3(N / 32, C2 / 32, B), 256, 0, stream>>>(
        x2, x2t, C2, N, (long long)C2 * N, (long long)N * C2);

    // 3. G1: img = w_img x x1t -> [C,N] f16, dual imgT [N,C]   (M=256,N=4096,K=512)
    gemm_bt<128, 128, 4, 4, 2, 2, 3, 1><<<dim3(N / 128, C / 128, B), 256, 0, stream>>>(
        wib, x1t, img, nullptr, nullptr, imgT, C, N, C1,
        0LL, (long long)N * C1, NC, NC);

    // 4. G2: kvT = x2t x w_txt -> [N,C] f16 (native), dual kv [C,N]  (M=4096,N=256,K=320)
    gemm_bt<128, 128, 4, 4, 2, 2, 3, 1><<<dim3(C / 128, N / 128, B), 256, 0, stream>>>(
        x2t, wtb, kvT, nullptr, nullptr, kv, N, C, C2,
        (long long)N * C2, 0LL, NC, NC);

    // 5. G3: attn += img x kv^T  [C,C] fp32, split-K=4 atomics  (M=N=256,K=4096)
    gemm_bt<64, 64, 2, 2, 2, 2, 5, 4><<<dim3(C / 64, C / 64, B * 4), 256, 0, stream>>>(
        img, kv, attn, nullptr, nullptr, nullptr, C, C, N,
        NC, NC, CC, 0LL);

    // 6. softmax rows -> f16
    softmax256<<<(B * C) / 4, 256, 0, stream>>>(attn, attns);

    // 7. G4: yT = gamma*(kvT x attns^T) + imgT -> [N,C] f16 native  (M=4096,N=256,K=256)
    gemm_bt<128, 128, 4, 4, 2, 2, 2, 1><<<dim3(C / 128, N / 128, B), 256, 0, stream>>>(
        kvT, attns, yT, imgT, gamma, nullptr, N, C, C,
        NC, CC, NC, 0LL);

    // 8. G5: out = w_out x yT^T -> [OC,N] fp32   (M=512,N=4096,K=256)
    gemm_bt<128, 128, 4, 4, 2, 2, 1, 1><<<dim3(N / 128, OC / 128, B), 256, 0, stream>>>(
        wob, yT, (float*)d_out, nullptr, nullptr, nullptr, OC, N, C,
        0LL, NC, (long long)OC * N, 0LL);
}

// Round 2
// 452.499 us; speedup vs baseline: 1.0839x; 1.0466x over previous
//
#include <hip/hip_runtime.h>
#include <stdint.h>

typedef _Float16 f16_t;
typedef _Float16 f16x4 __attribute__((ext_vector_type(4)));
typedef _Float16 f16x8 __attribute__((ext_vector_type(8)));
typedef float f32x4 __attribute__((ext_vector_type(4)));

// ---------------------------------------------------------------------------
// async global->LDS, 16B per lane. LDS dest is wave-uniform base + lane*16.
// ---------------------------------------------------------------------------
__device__ __forceinline__ void async16(const void* g, void* lds) {
    typedef __attribute__((address_space(3))) void lds_void;
    typedef __attribute__((address_space(1))) void glb_void;
    lds_void* l = (lds_void*)(unsigned int)(unsigned long long)lds;
    glb_void* gp = (glb_void*)(unsigned long long)g;
    __builtin_amdgcn_global_load_lds(gp, l, 16, 0, 0);
}

// ---------------------------------------------------------------------------
// prep: x1 transpose (32768 blocks) + x2 transpose (20480) + weight cvt (512)
// in ONE flat-grid launch. Transposes: 32x32 tiles via padded LDS.
// ---------------------------------------------------------------------------
__global__ __launch_bounds__(256) void prep(
    const float* __restrict__ x1, const float* __restrict__ x2,
    f16_t* __restrict__ x1t, f16_t* __restrict__ x2t,
    const float* __restrict__ w_img, f16_t* __restrict__ wib,
    const float* __restrict__ w_txt, f16_t* __restrict__ wtb,
    const float* __restrict__ w_out, f16_t* __restrict__ wob) {
    __shared__ float tile[32][33];
    const int id = blockIdx.x;
    const int t = threadIdx.x;
    if (id < 53248) {
        const float* ip; f16_t* op; int R, bx, by, bz;
        const int S = 4096;
        if (id < 32768) {
            R = 512; bx = id & 127; by = (id >> 7) & 15; bz = id >> 11;
            ip = x1 + (long long)bz * R * S;
            op = x1t + (long long)bz * S * R;
        } else {
            const int id2 = id - 32768;
            R = 320; bx = id2 & 127; by = (id2 >> 7) % 10; bz = id2 / 1280;
            ip = x2 + (long long)bz * R * S;
            op = x2t + (long long)bz * S * R;
        }
        const int s0 = bx * 32, r0 = by * 32;
        const int lr = t >> 3, lc = (t & 7) * 4;
        const float4 v = *(const float4*)(ip + (long long)(r0 + lr) * S + s0 + lc);
        tile[lr][lc + 0] = v.x;
        tile[lr][lc + 1] = v.y;
        tile[lr][lc + 2] = v.z;
        tile[lr][lc + 3] = v.w;
        __syncthreads();
        const int sr = t >> 3, rc = (t & 7) * 4;
        f16x4 o;
        o[0] = (f16_t)tile[rc + 0][sr];
        o[1] = (f16_t)tile[rc + 1][sr];
        o[2] = (f16_t)tile[rc + 2][sr];
        o[3] = (f16_t)tile[rc + 3][sr];
        *(f16x4*)(op + (long long)(s0 + sr) * R + r0 + rc) = o;
    } else {
        const int i = (id - 53248) * 256 + t;
        if (i < 512 * 256) wib[i] = (f16_t)w_img[i];
        if (i < 320 * 256) wtb[i] = (f16_t)w_txt[i];
        if (i < 512 * 256) wob[i] = (f16_t)w_out[i];
    }
}

// ---------------------------------------------------------------------------
// bt-GEMM:  C[m,n] = sum_k A[m,k] * Bt[n,k]   (both K-contiguous, fp16)
// BK=32, 16x16x32 f16 MFMA, 256 threads = 4 waves (WM x WN), TM x TN per wave.
// Double-buffered LDS, 2-phase pipeline: one barrier per K-step,
// STAGE(next) issued before ds_read+MFMA(cur) so HBM latency hides.
// MODE 0: f16 C.
// MODE 1: fp32 C.
// MODE 2: f16  gamma*acc + resid.
// MODE 3: f16 C + f16 C^T dual-write (LDS-staged transpose; Lt aliases the
//         dead staging buffers so LDS stays <= 80 KB for 2 blocks/CU).
// MODE 4: fp32 partial store per blockIdx.z slab (split-K, no atomics).
// ---------------------------------------------------------------------------
template <int BM, int BN, int TM, int TN, int WM, int WN, int MODE, int KSPLIT>
__global__ __launch_bounds__(256, 2)
void gemm_bt(const f16_t* __restrict__ A, const f16_t* __restrict__ B,
             void* __restrict__ C, const f16_t* __restrict__ resid,
             const float* __restrict__ gamma, f16_t* __restrict__ Ct,
             int M, int N, int K,
             long long strideA, long long strideB, long long strideC,
             long long strideCt) {
    constexpr int BK = 32;
    constexpr int AS = BM * BK;            // halfwords per A buffer
    constexpr int BS = BN * BK;
    constexpr int STG = AS + BS;           // halfwords per stage buffer
    constexpr int LT = (MODE == 3) ? BN * (BM + 8) : 0;
    constexpr int POOL = (2 * STG > LT) ? 2 * STG : LT;
    __shared__ __align__(16) f16_t pool[POOL];

    const int tid = threadIdx.x;
    const int wave = tid >> 6;
    const int lane = tid & 63;
    const int wm = wave / WN;
    const int wn = wave % WN;
    const int l16 = lane & 15;
    const int l4 = lane >> 4;

    const long long zb = (KSPLIT == 1) ? blockIdx.z : (blockIdx.z / KSPLIT);
    const int ks = (KSPLIT == 1) ? 0 : (blockIdx.z % KSPLIT);
    const int Ksl = K / KSPLIT;
    const f16_t* Ab = A + zb * strideA + (long long)blockIdx.y * BM * K;
    const f16_t* Bb = B + zb * strideB + (long long)blockIdx.x * BN * K;

    f32x4 zero = {0.f, 0.f, 0.f, 0.f};
    f32x4 acc[TM][TN];
#pragma unroll
    for (int i = 0; i < TM; ++i)
#pragma unroll
        for (int j = 0; j < TN; ++j) acc[i][j] = zero;

    auto stage = [&](int b, int k0) {
        f16_t* As = pool + b * STG;
        f16_t* Bs = As + AS;
#pragma unroll
        for (int r = 0; r < (BM * 4) / 256; ++r) {
            int seg = r * 256 + tid;
            const f16_t* g = Ab + (long long)(seg >> 2) * K + k0 + (seg & 3) * 8;
            async16(g, &As[(r * 256 + wave * 64) * 8]);
        }
#pragma unroll
        for (int r = 0; r < (BN * 4) / 256; ++r) {
            int seg = r * 256 + tid;
            const f16_t* g = Bb + (long long)(seg >> 2) * K + k0 + (seg & 3) * 8;
            async16(g, &Bs[(r * 256 + wave * 64) * 8]);
        }
    };
    auto compute = [&](int b) {
        const f16_t* As = pool + b * STG;
        const f16_t* Bs = As + AS;
        f16x8 af[TM], bfr[TN];
#pragma unroll
        for (int i = 0; i < TM; ++i)
            af[i] = *(const f16x8*)&As[((wm * TM + i) * 16 + l16) * BK + l4 * 8];
#pragma unroll
        for (int j = 0; j < TN; ++j)
            bfr[j] = *(const f16x8*)&Bs[((wn * TN + j) * 16 + l16) * BK + l4 * 8];
#pragma unroll
        for (int i = 0; i < TM; ++i)
#pragma unroll
            for (int j = 0; j < TN; ++j)
                acc[i][j] = __builtin_amdgcn_mfma_f32_16x16x32_f16(af[i], bfr[j], acc[i][j], 0, 0, 0);
    };

    const int kBeg = ks * Ksl;
    const int NT = Ksl / BK;
    stage(0, kBeg);
    __syncthreads();
    int cur = 0;
    for (int t = 1; t < NT; ++t) {
        stage(cur ^ 1, kBeg + t * BK);   // prefetch next tile (other buffer)
        compute(cur);                    // ds_read + MFMA current tile
        __syncthreads();                 // drains prefetch (vmcnt 0) + syncs
        cur ^= 1;
    }
    compute(cur);

    if (MODE == 3) __syncthreads();      // Lt aliases staging buffers

    // epilogue: C/D layout col = lane&15, row = (lane>>4)*4 + reg
    const int row0 = blockIdx.y * BM + wm * TM * 16;
    const int col0 = blockIdx.x * BN + wn * TN * 16;
    float g = (MODE == 2) ? gamma[0] : 0.f;
#pragma unroll
    for (int i = 0; i < TM; ++i) {
#pragma unroll
        for (int j = 0; j < TN; ++j) {
            f16x4 tq;
#pragma unroll
            for (int r = 0; r < 4; ++r) {
                int row = row0 + i * 16 + l4 * 4 + r;
                int col = col0 + j * 16 + l16;
                float v = acc[i][j][r];
                if (MODE == 4) {
                    long long idx = (long long)blockIdx.z * strideC + (long long)row * N + col;
                    ((float*)C)[idx] = v;
                } else {
                    long long idx = zb * strideC + (long long)row * N + col;
                    if (MODE == 0) {
                        ((f16_t*)C)[idx] = (f16_t)v;
                    } else if (MODE == 1) {
                        ((float*)C)[idx] = v;
                    } else if (MODE == 2) {
                        float im = (float)resid[idx];
                        ((f16_t*)C)[idx] = (f16_t)(g * v + im);
                    } else if (MODE == 3) {
                        ((f16_t*)C)[idx] = (f16_t)v;
                        tq[r] = (f16_t)v;
                    }
                }
            }
            if (MODE == 3) {
                int rl = wm * (TM * 16) + i * 16 + l4 * 4;
                int cl = wn * (TN * 16) + j * 16 + l16;
                *(f16x4*)&pool[cl * (BM + 8) + rl] = tq;
            }
        }
    }

    if (MODE == 3) {
        __syncthreads();
        const int bx0 = blockIdx.x * BN;
        const int by0 = blockIdx.y * BM;
        const long long cb = zb * strideCt;
        constexpr int TPR = BM / 8;        // threads per transposed row
        constexpr int RPI = 256 / TPR;     // rows per iteration
#pragma unroll
        for (int it = 0; it < BN / RPI; ++it) {
            int nl = it * RPI + (tid / TPR);
            int c8 = (tid % TPR) * 8;
            f16x8 v = *(const f16x8*)&pool[nl * (BM + 8) + c8];
            *(f16x8*)&Ct[cb + (long long)(bx0 + nl) * M + by0 + c8] = v;
        }
    }
}

// ---------------------------------------------------------------------------
// fused split-K reduce + softmax over rows of 256 -> fp16.
// Partials: [B][KS][256][256] fp32.  One wave per row, 4 rows per block.
// ---------------------------------------------------------------------------
template <int KS>
__global__ void softmax_red(const float* __restrict__ part, f16_t* __restrict__ out) {
    const int row = blockIdx.x * 4 + (threadIdx.x >> 6);   // [0, B*256)
    const int lane = threadIdx.x & 63;
    const int b = row >> 8, r = row & 255;
    const float* p = part + (long long)(b * KS) * 65536 + r * 256 + lane * 4;
    float4 v = *(const float4*)p;
#pragma unroll
    for (int k = 1; k < KS; ++k) {
        float4 u = *(const float4*)(p + (long long)k * 65536);
        v.x += u.x; v.y += u.y; v.z += u.z; v.w += u.w;
    }
    float m = fmaxf(fmaxf(v.x, v.y), fmaxf(v.z, v.w));
#pragma unroll
    for (int off = 32; off > 0; off >>= 1) m = fmaxf(m, __shfl_xor(m, off, 64));
    float e0 = __expf(v.x - m), e1 = __expf(v.y - m);
    float e2 = __expf(v.z - m), e3 = __expf(v.w - m);
    float s = e0 + e1 + e2 + e3;
#pragma unroll
    for (int off = 32; off > 0; off >>= 1) s += __shfl_xor(s, off, 64);
    const float inv = 1.0f / s;
    f16x4 o;
    o[0] = (f16_t)(e0 * inv);
    o[1] = (f16_t)(e1 * inv);
    o[2] = (f16_t)(e2 * inv);
    o[3] = (f16_t)(e3 * inv);
    *(f16x4*)(out + ((long long)row) * 256 + lane * 4) = o;
}

// ---------------------------------------------------------------------------
// Orchestration
//   prep: x1t [N,C1], x2t [N,C2] f16 + weight cvt          (1 launch)
//   G1: img [C,N] + imgT [N,C]     (BM=256: x1t read once)
//   G2: kv  [C,N] + kvT  [N,C]     (BM=256: x2t read once)
//   G3: partial[b][ks][C][C] fp32  (split-K=8, plain stores)
//   SM: attns = softmax(sum_ks partial) f16
//   G4: yT = gamma*(kvT x attns^T) + imgT  [N,C]
//   G5: out = w_out x yT^T  [OC,N] fp32    (BM=256: yT read twice not 4x)
// ---------------------------------------------------------------------------
extern "C" void kernel_launch(void* const* d_in, const int* in_sizes, int n_in,
                              void* d_out, int out_size, void* d_ws, size_t ws_size,
                              hipStream_t stream) {
    (void)in_sizes; (void)n_in; (void)out_size; (void)ws_size;

    const float* x1 = (const float*)d_in[0];     // [16,512,64,64]
    const float* x2 = (const float*)d_in[1];     // [16,320,64,64]
    const float* w_img = (const float*)d_in[2];  // [256,512]
    const float* w_txt = (const float*)d_in[3];  // [256,320]
    const float* w_out = (const float*)d_in[4];  // [512,256]
    const float* gamma = (const float*)d_in[5];  // [1]

    constexpr int B = 16, C1 = 512, C2 = 320, C = 256, N = 4096, OC = 512;
    constexpr int KS = 8;
    constexpr long long NC = (long long)N * C;       // 1048576
    constexpr long long CC = (long long)C * C;       // 65536

    // ws layout (bytes): peak 103,448,576 (~98.7 MiB; round-0 proved >=109.7 OK)
    char* ws = (char*)d_ws;
    f16_t* wib   = (f16_t*)(ws + 0);          // 262144
    f16_t* wtb   = (f16_t*)(ws + 262144);     // 163840
    f16_t* wob   = (f16_t*)(ws + 425984);     // 262144
    f16_t* img   = (f16_t*)(ws + 688128);     // 33554432
    f16_t* imgT  = (f16_t*)(ws + 34242560);   // 33554432
    f16_t* kvT   = (f16_t*)(ws + 67796992);   // 33554432 -> 101351424
    f16_t* attns = (f16_t*)(ws + 101351424);  // 2097152  -> 103448576
    f16_t* yT    = img;                       // img dead after G3

    // d_out as scratch; G5 overwrites all of it
    char* oc = (char*)d_out;
    f16_t* x1t  = (f16_t*)(oc);               // [0, 67108864)   dead after G1
    f16_t* x2t  = (f16_t*)(oc + 67108864);    // [.., 109051904) dead after G2
    f16_t* kv   = (f16_t*)(oc);               // [0, 33554432)   after x1t dead
    float* part = (float*)(oc + 33554432);    // 8*16*65536*4 = 33554432 -> 67108864

    // 1. prep: both transposes + all weight cvts, one flat launch
    prep<<<53760, 256, 0, stream>>>(x1, x2, x1t, x2t, w_img, wib, w_txt, wtb, w_out, wob);

    // 2. G1: img = w_img x x1t, dual imgT   (M=256,N=4096,K=512, BM=256)
    gemm_bt<256, 128, 8, 4, 2, 2, 3, 1><<<dim3(N / 128, 1, B), 256, 0, stream>>>(
        wib, x1t, img, nullptr, nullptr, imgT, C, N, C1,
        0LL, (long long)N * C1, NC, NC);

    // 3. G2: kv = w_txt x x2t, dual kvT     (M=256,N=4096,K=320, BM=256)
    gemm_bt<256, 128, 8, 4, 2, 2, 3, 1><<<dim3(N / 128, 1, B), 256, 0, stream>>>(
        wtb, x2t, kv, nullptr, nullptr, kvT, C, N, C2,
        0LL, (long long)N * C2, NC, NC);

    // 4. G3: partial[z] = img x kv^T slice  (M=N=256,K=4096, split-K=8)
    gemm_bt<64, 64, 2, 2, 2, 2, 4, KS><<<dim3(C / 64, C / 64, B * KS), 256, 0, stream>>>(
        img, kv, part, nullptr, nullptr, nullptr, C, C, N,
        NC, NC, CC, 0LL);

    // 5. fused reduce + softmax -> f16
    softmax_red<KS><<<(B * C) / 4, 256, 0, stream>>>(part, attns);

    // 6. G4: yT = gamma*(kvT x attns^T) + imgT   (M=4096,N=256,K=256)
    gemm_bt<128, 128, 4, 4, 2, 2, 2, 1><<<dim3(C / 128, N / 128, B), 256, 0, stream>>>(
        kvT, attns, yT, imgT, gamma, nullptr, N, C, C,
        NC, CC, NC, 0LL);

    // 7. G5: out = w_out x yT^T   (M=512,N=4096,K=256, BM=256)
    gemm_bt<256, 128, 8, 4, 2, 2, 1, 1><<<dim3(N / 128, OC / 256, B), 256, 0, stream>>>(
        wob, yT, (float*)d_out, nullptr, nullptr, nullptr, OC, N, C,
        0LL, NC, (long long)OC * N, 0LL);
}

// Round 4
// 391.936 us; speedup vs baseline: 1.2514x; 1.1545x over previous
//
#include <hip/hip_runtime.h>
#include <stdint.h>

typedef _Float16 f16_t;
typedef _Float16 f16x4 __attribute__((ext_vector_type(4)));
typedef _Float16 f16x8 __attribute__((ext_vector_type(8)));
typedef float f32x4 __attribute__((ext_vector_type(4)));

// ---------------------------------------------------------------------------
// async global->LDS, 16B per lane. LDS dest is wave-uniform base + lane*16.
// ---------------------------------------------------------------------------
__device__ __forceinline__ void async16(const void* g, void* lds) {
    typedef __attribute__((address_space(3))) void lds_void;
    typedef __attribute__((address_space(1))) void glb_void;
    lds_void* l = (lds_void*)(unsigned int)(unsigned long long)lds;
    glb_void* gp = (glb_void*)(unsigned long long)g;
    __builtin_amdgcn_global_load_lds(gp, l, 16, 0, 0);
}

// ---------------------------------------------------------------------------
// weights fp32 -> f16 (three arrays, one launch)
// ---------------------------------------------------------------------------
__global__ void cvt3(const float* __restrict__ a, f16_t* __restrict__ oa, int na,
                     const float* __restrict__ b, f16_t* __restrict__ ob, int nb,
                     const float* __restrict__ c, f16_t* __restrict__ oc, int nc) {
    int i = blockIdx.x * 256 + threadIdx.x;
    if (i < na) oa[i] = (f16_t)a[i];
    if (i < nb) ob[i] = (f16_t)b[i];
    if (i < nc) oc[i] = (f16_t)c[i];
}

// ---------------------------------------------------------------------------
// bt-GEMM:  C[m,n] = sum_k A[m,k] * Bt[n,k]
// BK=32, 16x16x32 f16 MFMA, 256 threads = 4 waves (WM x WN), TM x TN per wave.
// Double-buffered LDS, one barrier per K-step.
//
// FUSET=0: B is f16 [N][K] K-contiguous, staged via global_load_lds.
// FUSET=1: B is fp32 [K][N] NATURAL layout (row k, n-contiguous).
//          Staging: coalesced float4 loads -> reg cvt f16 -> ds_write_b64 into
//          [BK][BN] with XOR bank-swizzle  hw = k*BN + (n ^ 8*((k>>3)&3)).
//          Fragment read: 8x scalar ds_read_u16 at hw = k*BN + (n ^ 8*l4)
//          (same swizzle: (k>>3)&3 == l4 for all 8 k of a fragment).
//          Fuses the input transpose+cvt into the GEMM (no HBM round-trip).
//          Interpretation-free: plain C++ index algebra, no tr_read.
//
// MODE 0: f16 C.   MODE 1: fp32 C.   MODE 2: f16 gamma*acc + resid.
// MODE 3: f16 C + f16 C^T dual-write (LDS-staged, aliases staging pool).
// MODE 4: fp32 partial store per blockIdx.z slab (split-K, no atomics).
// ---------------------------------------------------------------------------
template <int BM, int BN, int TM, int TN, int WM, int WN, int MODE, int KSPLIT, int FUSET>
__global__ __launch_bounds__(256, 2)
void gemm_bt(const f16_t* __restrict__ A, const f16_t* __restrict__ B16,
             const float* __restrict__ Bf32,
             void* __restrict__ C, const f16_t* __restrict__ resid,
             const float* __restrict__ gamma, f16_t* __restrict__ Ct,
             int M, int N, int K,
             long long strideA, long long strideB, long long strideC,
             long long strideCt) {
    constexpr int BK = 32;
    static_assert(FUSET == 0 || (BN == 128), "fused path assumes BN=128");
    constexpr int ASZ = BM * BK;                                   // halfwords
    constexpr int BSZ = BN * BK;
    constexpr int STG = 2 * ASZ + 2 * BSZ;
    constexpr int LT = (MODE == 3) ? BN * (BM + 8) : 0;
    constexpr int POOL = (STG > LT) ? STG : LT;
    __shared__ __align__(16) f16_t pool[POOL];

    const int tid = threadIdx.x;
    const int wave = tid >> 6;
    const int lane = tid & 63;
    const int wm = wave / WN;
    const int wn = wave % WN;
    const int l16 = lane & 15;
    const int l4 = lane >> 4;

    const long long zb = (KSPLIT == 1) ? blockIdx.z : (blockIdx.z / KSPLIT);
    const int ks = (KSPLIT == 1) ? 0 : (blockIdx.z % KSPLIT);
    const int Ksl = K / KSPLIT;
    const f16_t* Ab = A + zb * strideA + (long long)blockIdx.y * BM * K;
    const f16_t* Bb = (FUSET == 0) ? (B16 + zb * strideB + (long long)blockIdx.x * BN * K) : nullptr;
    const float* BfB = FUSET ? (Bf32 + zb * strideB + blockIdx.x * BN) : nullptr;

    f32x4 zero = {0.f, 0.f, 0.f, 0.f};
    f32x4 acc[TM][TN];
#pragma unroll
    for (int i = 0; i < TM; ++i)
#pragma unroll
        for (int j = 0; j < TN; ++j) acc[i][j] = zero;

    // ---- staging -----------------------------------------------------------
    auto stageA = [&](int b, int k0) {
        f16_t* As = pool + b * ASZ;
#pragma unroll
        for (int r = 0; r < (BM * 4) / 256; ++r) {
            int seg = r * 256 + tid;
            const f16_t* g = Ab + (long long)(seg >> 2) * K + k0 + (seg & 3) * 8;
            async16(g, &As[(r * 256 + wave * 64) * 8]);
        }
    };
    auto stageB16 = [&](int b, int k0) {
#pragma unroll
        for (int r = 0; r < (BN * 4) / 256; ++r) {
            int seg = r * 256 + tid;
            const f16_t* g = Bb + (long long)(seg >> 2) * K + k0 + (seg & 3) * 8;
            async16(g, &pool[2 * ASZ + b * BSZ + (r * 256 + wave * 64) * 8]);
        }
    };
    // fused-B: thread t owns row fk = t>>3, 4 float4 at n = fc + i*32
    float4 br[4];
    const int fk = tid >> 3;
    const int fc = (tid & 7) * 4;
    const int fswz = ((fk >> 3) & 3) * 8;
    auto loadB = [&](int k0) {
#pragma unroll
        for (int i = 0; i < 4; ++i)
            br[i] = *(const float4*)(BfB + (long long)(k0 + fk) * N + fc + i * 32);
    };
    auto writeB = [&](int b) {
        f16_t* Bs = pool + 2 * ASZ + b * BSZ;
#pragma unroll
        for (int i = 0; i < 4; ++i) {
            int n4 = fc + i * 32;
            f16x4 h;
            h[0] = (f16_t)br[i].x; h[1] = (f16_t)br[i].y;
            h[2] = (f16_t)br[i].z; h[3] = (f16_t)br[i].w;
            *(f16x4*)&Bs[fk * BN + (n4 ^ fswz)] = h;
        }
    };

    // ---- compute one K-step ------------------------------------------------
    auto compute = [&](int b) {
        const f16_t* As = pool + b * ASZ;
        f16x8 af[TM], bfr[TN];
#pragma unroll
        for (int i = 0; i < TM; ++i)
            af[i] = *(const f16x8*)&As[((wm * TM + i) * 16 + l16) * BK + l4 * 8];
        if (FUSET) {
            const f16_t* Bs = pool + 2 * ASZ + b * BSZ;
#pragma unroll
            for (int j = 0; j < TN; ++j) {
                const int nj = ((wn * TN + j) * 16 + l16) ^ (l4 * 8);
                f16x8 t;
#pragma unroll
                for (int e = 0; e < 8; ++e)
                    t[e] = Bs[(l4 * 8 + e) * BN + nj];
                bfr[j] = t;
            }
        } else {
            const f16_t* Bs = pool + 2 * ASZ + b * BSZ;
#pragma unroll
            for (int j = 0; j < TN; ++j)
                bfr[j] = *(const f16x8*)&Bs[((wn * TN + j) * 16 + l16) * BK + l4 * 8];
        }
#pragma unroll
        for (int i = 0; i < TM; ++i)
#pragma unroll
            for (int j = 0; j < TN; ++j)
                acc[i][j] = __builtin_amdgcn_mfma_f32_16x16x32_f16(af[i], bfr[j], acc[i][j], 0, 0, 0);
    };

    // ---- main loop ---------------------------------------------------------
    const int kBeg = ks * Ksl;
    const int NT = Ksl / BK;
    int cur = 0;
    if (FUSET) {
        loadB(kBeg);
        stageA(0, kBeg);
        writeB(0);
        __syncthreads();
        for (int t = 1; t < NT; ++t) {
            loadB(kBeg + t * BK);            // prefetch B t+0 regs (global)
            stageA(cur ^ 1, kBeg + t * BK);  // prefetch A (async LDS)
            compute(cur);
            writeB(cur ^ 1);                 // cvt + ds_write after compute
            __syncthreads();
            cur ^= 1;
        }
        compute(cur);
    } else {
        stageA(0, kBeg);
        stageB16(0, kBeg);
        __syncthreads();
        for (int t = 1; t < NT; ++t) {
            stageA(cur ^ 1, kBeg + t * BK);
            stageB16(cur ^ 1, kBeg + t * BK);
            compute(cur);
            __syncthreads();
            cur ^= 1;
        }
        compute(cur);
    }

    if (MODE == 3) __syncthreads();      // Lt aliases staging pool

    // ---- epilogue: C/D layout col = lane&15, row = (lane>>4)*4 + reg -------
    const int row0 = blockIdx.y * BM + wm * TM * 16;
    const int col0 = blockIdx.x * BN + wn * TN * 16;
    float g = (MODE == 2) ? gamma[0] : 0.f;
#pragma unroll
    for (int i = 0; i < TM; ++i) {
#pragma unroll
        for (int j = 0; j < TN; ++j) {
            f16x4 tq;
#pragma unroll
            for (int r = 0; r < 4; ++r) {
                int row = row0 + i * 16 + l4 * 4 + r;
                int col = col0 + j * 16 + l16;
                float v = acc[i][j][r];
                if (MODE == 4) {
                    long long idx = (long long)blockIdx.z * strideC + (long long)row * N + col;
                    ((float*)C)[idx] = v;
                } else {
                    long long idx = zb * strideC + (long long)row * N + col;
                    if (MODE == 0) {
                        ((f16_t*)C)[idx] = (f16_t)v;
                    } else if (MODE == 1) {
                        ((float*)C)[idx] = v;
                    } else if (MODE == 2) {
                        float im = (float)resid[idx];
                        ((f16_t*)C)[idx] = (f16_t)(g * v + im);
                    } else if (MODE == 3) {
                        ((f16_t*)C)[idx] = (f16_t)v;
                        tq[r] = (f16_t)v;
                    }
                }
            }
            if (MODE == 3) {
                int rl = wm * (TM * 16) + i * 16 + l4 * 4;
                int cl = wn * (TN * 16) + j * 16 + l16;
                *(f16x4*)&pool[cl * (BM + 8) + rl] = tq;
            }
        }
    }

    if (MODE == 3) {
        __syncthreads();
        const int bx0 = blockIdx.x * BN;
        const int by0 = blockIdx.y * BM;
        const long long cb = zb * strideCt;
        constexpr int TPR = BM / 8;        // threads per transposed row
        constexpr int RPI = 256 / TPR;     // rows per iteration
#pragma unroll
        for (int it = 0; it < BN / RPI; ++it) {
            int nl = it * RPI + (tid / TPR);
            int c8 = (tid % TPR) * 8;
            f16x8 v = *(const f16x8*)&pool[nl * (BM + 8) + c8];
            *(f16x8*)&Ct[cb + (long long)(bx0 + nl) * M + by0 + c8] = v;
        }
    }
}

// ---------------------------------------------------------------------------
// fused split-K reduce + softmax over rows of 256 -> fp16.
// Partials: [B][KS][256][256] fp32.  One wave per row, 4 rows per block.
// ---------------------------------------------------------------------------
template <int KS>
__global__ void softmax_red(const float* __restrict__ part, f16_t* __restrict__ out) {
    const int row = blockIdx.x * 4 + (threadIdx.x >> 6);   // [0, B*256)
    const int lane = threadIdx.x & 63;
    const int b = row >> 8, r = row & 255;
    const float* p = part + (long long)(b * KS) * 65536 + r * 256 + lane * 4;
    float4 v = *(const float4*)p;
#pragma unroll
    for (int k = 1; k < KS; ++k) {
        float4 u = *(const float4*)(p + (long long)k * 65536);
        v.x += u.x; v.y += u.y; v.z += u.z; v.w += u.w;
    }
    float m = fmaxf(fmaxf(v.x, v.y), fmaxf(v.z, v.w));
#pragma unroll
    for (int off = 32; off > 0; off >>= 1) m = fmaxf(m, __shfl_xor(m, off, 64));
    float e0 = __expf(v.x - m), e1 = __expf(v.y - m);
    float e2 = __expf(v.z - m), e3 = __expf(v.w - m);
    float s = e0 + e1 + e2 + e3;
#pragma unroll
    for (int off = 32; off > 0; off >>= 1) s += __shfl_xor(s, off, 64);
    const float inv = 1.0f / s;
    f16x4 o;
    o[0] = (f16_t)(e0 * inv);
    o[1] = (f16_t)(e1 * inv);
    o[2] = (f16_t)(e2 * inv);
    o[3] = (f16_t)(e3 * inv);
    *(f16x4*)(out + ((long long)row) * 256 + lane * 4) = o;
}

// ---------------------------------------------------------------------------
// Orchestration (no standalone input transposes):
//   cvt3: weights -> f16
//   G1 (FUSET): img [C,N] + imgT [N,C]  directly from fp32 x1
//   G2 (FUSET): kv  [C,N] + kvT  [N,C]  directly from fp32 x2
//   G3: partial[b][ks][C][C] fp32  (128^2 tiles, split-K=8, plain stores)
//   SM: attns = softmax(sum_ks partial) f16
//   G4: yT = gamma*(kvT x attns^T) + imgT  [N,C]
//   G5: out = w_out x yT^T  [OC,N] fp32
// ---------------------------------------------------------------------------
extern "C" void kernel_launch(void* const* d_in, const int* in_sizes, int n_in,
                              void* d_out, int out_size, void* d_ws, size_t ws_size,
                              hipStream_t stream) {
    (void)in_sizes; (void)n_in; (void)out_size; (void)ws_size;

    const float* x1 = (const float*)d_in[0];     // [16,512,64,64]
    const float* x2 = (const float*)d_in[1];     // [16,320,64,64]
    const float* w_img = (const float*)d_in[2];  // [256,512]
    const float* w_txt = (const float*)d_in[3];  // [256,320]
    const float* w_out = (const float*)d_in[4];  // [512,256]
    const float* gamma = (const float*)d_in[5];  // [1]

    constexpr int B = 16, C1 = 512, C2 = 320, C = 256, N = 4096, OC = 512;
    constexpr int KS = 8;
    constexpr long long NC = (long long)N * C;       // 1048576
    constexpr long long CC = (long long)C * C;       // 65536

    // ws layout (bytes): peak 103,448,576 (~98.7 MiB)
    char* ws = (char*)d_ws;
    f16_t* wib   = (f16_t*)(ws + 0);          // 262144
    f16_t* wtb   = (f16_t*)(ws + 262144);     // 163840
    f16_t* wob   = (f16_t*)(ws + 425984);     // 262144
    f16_t* img   = (f16_t*)(ws + 688128);     // 33554432
    f16_t* imgT  = (f16_t*)(ws + 34242560);   // 33554432
    f16_t* kvT   = (f16_t*)(ws + 67796992);   // 33554432 -> 101351424
    f16_t* attns = (f16_t*)(ws + 101351424);  // 2097152  -> 103448576
    f16_t* yT    = img;                       // img dead after G3

    // d_out as scratch; G5 overwrites all of it
    char* oc = (char*)d_out;
    f16_t* kv   = (f16_t*)(oc);               // [0, 33554432)
    float* part = (float*)(oc + 33554432);    // 8*16*65536*4 = 33554432 -> 67108864

    // 1. weights -> f16
    cvt3<<<512, 256, 0, stream>>>(w_img, wib, C * C1, w_txt, wtb, C * C2, w_out, wob, OC * C);

    // 2. G1: img = w_img x x1 (fused transpose+cvt), dual imgT  (M=256,N=4096,K=512)
    gemm_bt<256, 128, 8, 4, 2, 2, 3, 1, 1><<<dim3(N / 128, 1, B), 256, 0, stream>>>(
        wib, nullptr, x1, img, nullptr, nullptr, imgT, C, N, C1,
        0LL, (long long)C1 * N, NC, NC);

    // 3. G2: kv = w_txt x x2 (fused), dual kvT   (M=256,N=4096,K=320)
    gemm_bt<256, 128, 8, 4, 2, 2, 3, 1, 1><<<dim3(N / 128, 1, B), 256, 0, stream>>>(
        wtb, nullptr, x2, kv, nullptr, nullptr, kvT, C, N, C2,
        0LL, (long long)C2 * N, NC, NC);

    // 4. G3: partial[z] = img x kv^T slice  (M=N=256,K=4096, 128^2, split-K=8)
    gemm_bt<128, 128, 4, 4, 2, 2, 4, KS, 0><<<dim3(C / 128, C / 128, B * KS), 256, 0, stream>>>(
        img, kv, nullptr, part, nullptr, nullptr, nullptr, C, C, N,
        NC, NC, CC, 0LL);

    // 5. fused reduce + softmax -> f16
    softmax_red<KS><<<(B * C) / 4, 256, 0, stream>>>(part, attns);

    // 6. G4: yT = gamma*(kvT x attns^T) + imgT   (M=4096,N=256,K=256)
    gemm_bt<128, 128, 4, 4, 2, 2, 2, 1, 0><<<dim3(C / 128, N / 128, B), 256, 0, stream>>>(
        kvT, attns, nullptr, yT, imgT, gamma, nullptr, N, C, C,
        NC, CC, NC, 0LL);

    // 7. G5: out = w_out x yT^T   (M=512,N=4096,K=256)
    gemm_bt<256, 128, 8, 4, 2, 2, 1, 1, 0><<<dim3(N / 128, OC / 256, B), 256, 0, stream>>>(
        wob, yT, nullptr, (float*)d_out, nullptr, nullptr, nullptr, OC, N, C,
        0LL, NC, (long long)OC * N, 0LL);
}